// Round 4
// baseline (223.365 us; speedup 1.0000x reference)
//
#include <hip/hip_runtime.h>

// Word2VecEmbedding: out[b,s,:] = table[ids[b,s]] except UNK tokens (~5%)
// get the masked mean of the +-2 context window's embeddings.
//   VOCAB=50000, DIM=300, PAD=0, UNK=1, CTX_W=2, B=32, S=4096
// d_in[0] = input_ids (B*S int32), d_in[1] = table (VOCAB*DIM f32)
// d_out   = (B,S,DIM) f32
//
// R3: ITEMS=8 per thread; 9,830,400 float4 = 4800 blocks x 2048 exactly, so
// the main kernel has ZERO bounds checks: 8 independent ids loads, then 8
// independent table gathers, rare UNK repair, 8 nontemporal streaming stores.
// Floor: 157MB write + ~56MB compulsory read ~= 35us at 6.3TB/s.

#define PAD_ID 0
#define UNK_ID 1
#define SEQ    4096
#define DIM4   75
#define ITEMS  8
#define BLOCK  256

typedef float vf4 __attribute__((ext_vector_type(4)));

__device__ __forceinline__ vf4 unk_repair(const int* __restrict__ ids,
                                          const vf4* __restrict__ table4,
                                          int t, int d)
{
    int s = t & (SEQ - 1);
    vf4 acc = (vf4)0.f;
    float cnt = 0.f;
#pragma unroll
    for (int k = -2; k <= 2; ++k) {
        if (k == 0) continue;
        int sn = s + k;
        if (sn < 0 || sn >= SEQ) continue;          // zero-pad at row edges
        int idn = ids[t + k];
        if (idn == PAD_ID || idn == UNK_ID) continue;
        acc += table4[idn * DIM4 + d];
        cnt += 1.f;
    }
    return acc * (1.f / (cnt + 1e-8f));             // cnt==0 -> zeros
}

// Main kernel: grid covers total4 exactly, no bounds checks.
__global__ __launch_bounds__(BLOCK) void w2v_embed_main(
    const int* __restrict__ ids,
    const vf4* __restrict__ table4,
    vf4* __restrict__ out4)
{
    const int base = blockIdx.x * (BLOCK * ITEMS) + threadIdx.x;

    int tt[ITEMS], dd[ITEMS], idv[ITEMS];

    // 8 independent ids loads in flight (contiguous, L1/L2-hot)
#pragma unroll
    for (int u = 0; u < ITEMS; ++u) {
        int i = base + u * BLOCK;
        int t = i / DIM4;                 // magic-mul
        tt[u] = t;
        dd[u] = i - t * DIM4;
        idv[u] = ids[t];
    }

    // 8 independent table gathers in flight (coalesced: consecutive lanes
    // read consecutive float4s of the same row)
    vf4 val[ITEMS];
#pragma unroll
    for (int u = 0; u < ITEMS; ++u) {
        val[u] = table4[idv[u] * DIM4 + dd[u]];
    }

    // Rare UNK repair (~5% of tokens)
#pragma unroll
    for (int u = 0; u < ITEMS; ++u) {
        if (idv[u] == UNK_ID) val[u] = unk_repair(ids, table4, tt[u], dd[u]);
    }

    // Streaming nontemporal stores: don't evict the 60MB table from L2/L3.
#pragma unroll
    for (int u = 0; u < ITEMS; ++u) {
        __builtin_nontemporal_store(val[u], &out4[base + u * BLOCK]);
    }
}

// Guarded tail for the (unused at these sizes) remainder.
__global__ __launch_bounds__(BLOCK) void w2v_embed_tail(
    const int* __restrict__ ids,
    const vf4* __restrict__ table4,
    vf4* __restrict__ out4,
    int start, int total4)
{
    int i = start + blockIdx.x * BLOCK + threadIdx.x;
    if (i >= total4) return;
    int t = i / DIM4;
    int d = i - t * DIM4;
    int id = ids[t];
    vf4 v = table4[id * DIM4 + d];
    if (id == UNK_ID) v = unk_repair(ids, table4, t, d);
    __builtin_nontemporal_store(v, &out4[i]);
}

extern "C" void kernel_launch(void* const* d_in, const int* in_sizes, int n_in,
                              void* d_out, int out_size, void* d_ws, size_t ws_size,
                              hipStream_t stream)
{
    const int* ids    = (const int*)d_in[0];
    const vf4* table4 = (const vf4*)d_in[1];
    vf4*       out4   = (vf4*)d_out;

    int total4 = out_size / 4;                 // 9,830,400
    int per_block = BLOCK * ITEMS;             // 2048
    int grid = total4 / per_block;             // 4800 (exact)
    if (grid > 0)
        w2v_embed_main<<<grid, BLOCK, 0, stream>>>(ids, table4, out4);
    int done = grid * per_block;
    int rem  = total4 - done;                  // 0 at these sizes
    if (rem > 0) {
        int tgrid = (rem + BLOCK - 1) / BLOCK;
        w2v_embed_tail<<<tgrid, BLOCK, 0, stream>>>(ids, table4, out4, done, total4);
    }
}